// Round 10
// baseline (1983.395 us; speedup 1.0000x reference)
//
#include <hip/hip_runtime.h>
#include <stdint.h>

#define CDIM   4096
#define S_N    3355443
#define R_N    1048576
#define N1     (S_N + R_N)                 // 4404019 contributions
#define TILE   4096
#define WPT    (TILE / 256)                // 16 elements per thread
#define NTILES ((N1 + TILE - 1) / TILE)    // 1076
#define NPAD   (NTILES * TILE)             // 4407296
#define NSB    (NPAD / 256)                // 17216 (== NTILES*16)
#define SR_CH  ((NTILES + 255) / 256)      // 5 row entries per thread in scan
#define PAD_KEY 0xFFFFFFu
#define PAD_VAL 0xFFFFFFFFu                // impossible value bits (sums are >= +0)
#define SENT  (((uint64_t)PAD_KEY << 32) | (uint64_t)PAD_VAL)
#define ADJF  ((float)(1.0 - (3355443.0 / 16777216.0) * (1.0 - 0.95)))

// Exclusive block-wide scan over 256 threads (4 waves). Contains syncthreads.
static __device__ __forceinline__ unsigned blockScanExcl(unsigned v, unsigned t,
                                                         unsigned* lw, unsigned* tot){
  unsigned lane = t & 63u, w = t >> 6;
  unsigned x = v;
  #pragma unroll
  for (int off = 1; off < 64; off <<= 1){
    unsigned y = __shfl_up(x, off, 64);
    if (lane >= (unsigned)off) x += y;
  }
  if (lane == 63u) lw[w] = x;
  __syncthreads();
  unsigned woff = 0;
  for (unsigned i = 0; i < w; i++) woff += lw[i];
  *tot = lw[0] + lw[1] + lw[2] + lw[3];
  __syncthreads();
  return x + woff - v;
}

// Recompute element i of the contribution array from the raw inputs.
// Samples first, then decayed buffer entries, then padding -> stable sort
// preserves segment_sum's accumulation order exactly.
static __device__ __forceinline__ uint64_t make_elem(unsigned i,
                                                     const int* __restrict__ sidx,
                                                     const int* __restrict__ ridx,
                                                     const float* __restrict__ rval,
                                                     const float* __restrict__ grad){
  uint32_t key, vb;
  if (i < S_N){
    key = (uint32_t)sidx[i];
    vb  = __float_as_uint(fabsf(grad[i]));
  } else if (i < N1){
    unsigned j = i - S_N;
    int2 rc = ((const int2* __restrict__)ridx)[j];
    key = (uint32_t)(rc.x * CDIM + rc.y);
    vb = __float_as_uint(ADJF * rval[j]);
  } else {
    key = PAD_KEY; vb = PAD_VAL;
  }
  return ((uint64_t)key << 32) | (uint64_t)vb;
}

// Zero the 8 ticket counters (workspace is re-poisoned every run: mandatory).
__global__ __launch_bounds__(64) void k_zero(unsigned* __restrict__ d){
  if (threadIdx.x < 8u) d[threadIdx.x] = 0u;
}

// ---- Fused per-tile histogram + single-counter ticket barrier + row scan ---
// All NTILES blocks are co-resident (1.2 KB LDS, 8 blocks/CU -> 2048 slots >
// 1076), so the barrier cannot deadlock. Each block publishes its hist column,
// takes a ticket; the LAST 256 ticket holders spin on the ONE counter until it
// reaches NTILES (bounded: the tail of this kernel's own hist work), then each
// scans one digit row into exclusive tile prefixes + dtot. This replaces the
// separate k_scanrows dispatch of rounds 4-9.
// HM 0: key byte-32 hist from raw inputs (sidx + ridx.y only)
// HM 1: hist of (in >> shift) & 0xFF over the full NPAD array
// HM 2: dense prefix [0, aux[0]) with SENT synthesis beyond (tail tiles
//       write their constant column)
// HM 3: gapped candidate layout, aux = per-256-slot sub-block counts
template <int HM>
__global__ __launch_bounds__(256) void k_histscan(const uint64_t* __restrict__ in,
                                                  const int* __restrict__ sidx,
                                                  const int* __restrict__ ridx,
                                                  unsigned shift,
                                                  unsigned* __restrict__ gh,
                                                  unsigned* __restrict__ dtot,
                                                  const unsigned* __restrict__ aux,
                                                  unsigned* __restrict__ done){
  __shared__ unsigned h[256];
  __shared__ unsigned lw[4];
  __shared__ unsigned tick;
  unsigned t = threadIdx.x, b = blockIdx.x;
  // ---- hist phase ----
  unsigned Un = 0u;
  bool skiphist = false;                   // uniform per block
  if (HM == 2){
    Un = aux[0];
    if ((size_t)b * TILE >= (size_t)Un){
      gh[t * NTILES + b] = (t == 255u) ? (unsigned)TILE : 0u;
      skiphist = true;
    }
  }
  if (!skiphist){
    h[t] = 0; __syncthreads();
    size_t base = (size_t)b * TILE;
    #pragma unroll
    for (int r = 0; r < WPT; r++){
      if (HM == 0){
        unsigned i = (unsigned)(base + (size_t)r*256 + t);
        unsigned kb;
        if (i < S_N)       kb = ((uint32_t)sidx[i]) & 0xFFu;
        else if (i < N1)   kb = ((uint32_t)ridx[2u*(i - S_N) + 1u]) & 0xFFu;
        else               kb = 0xFFu;                      // PAD_KEY & 0xFF
        atomicAdd(&h[kb], 1u);
      } else if (HM == 1){
        uint64_t e = in[base + (size_t)r*256 + t];
        atomicAdd(&h[(unsigned)((e >> shift) & 0xFF)], 1u);
      } else if (HM == 2){
        unsigned i = (unsigned)(base + (size_t)r*256 + t);
        uint64_t e = (i < Un) ? in[i] : SENT;
        atomicAdd(&h[(unsigned)((e >> shift) & 0xFF)], 1u);
      } else {                                              // HM == 3
        unsigned cnt = aux[b * 16u + (unsigned)r];
        uint64_t e = (t < cnt) ? in[base + (size_t)r*256 + t] : SENT;
        atomicAdd(&h[(unsigned)((e >> shift) & 0xFF)], 1u);
      }
    }
    __syncthreads();
    gh[t * NTILES + b] = h[t];
  }
  // ---- ticket barrier (single word; bounded spin; all blocks resident) ----
  __threadfence();
  __syncthreads();
  if (t == 0u)
    tick = __hip_atomic_fetch_add(done, 1u, __ATOMIC_RELEASE,
                                  __HIP_MEMORY_SCOPE_AGENT);
  __syncthreads();
  unsigned ticket = tick;
  if (ticket < (unsigned)(NTILES - 256)) return;            // not a scanner
  unsigned row = ticket - (unsigned)(NTILES - 256);
  if (t == 0u){
    while (__hip_atomic_load(done, __ATOMIC_ACQUIRE,
                             __HIP_MEMORY_SCOPE_AGENT) < (unsigned)NTILES)
      __builtin_amdgcn_s_sleep(2);
  }
  __syncthreads();
  __threadfence();
  // ---- scan phase: this block owns digit row `row` exclusively ----
  unsigned rowbase = row * NTILES;
  unsigned vals[SR_CH];
  unsigned s = 0;
  #pragma unroll
  for (int k = 0; k < SR_CH; k++){
    unsigned i = t * SR_CH + (unsigned)k;
    vals[k] = (i < NTILES) ? gh[rowbase + i] : 0u;
    s += vals[k];
  }
  unsigned tot;
  unsigned carry = blockScanExcl(s, t, lw, &tot);
  #pragma unroll
  for (int k = 0; k < SR_CH; k++){
    unsigned i = t * SR_CH + (unsigned)k;
    if (i < NTILES){ gh[rowbase + i] = carry; carry += vals[k]; }
  }
  if (t == 0) dtot[row] = tot;
}

// ---- LDS-staged stable radix scatter (unchanged from round 9) -------------
// MODE 0: plain pass over the full NPAD array.
// MODE 1: M-mode (value LSD over dense [0,M)): synthesize SENT for
//         i >= nsyn[0]; write only dest < mskip[0].
// MODE 2: M-mode final: emit output rows for dest < R_N.
// MODE 3: build-recompute: elements recomputed from raw inputs (key pass 1).
// MODE 4: GAPPED compact with FUSED CUT: element validity from hcnt[sb];
//         M computed in phase B from the dtot scan; block 0 persists mvar.
template <int MODE>
__device__ __forceinline__ void scatter_body(const uint64_t* __restrict__ in,
                                             uint64_t* __restrict__ out,
                                             float* __restrict__ fout,
                                             unsigned shift,
                                             const unsigned* __restrict__ gh,
                                             const unsigned* __restrict__ dtot,
                                             const unsigned* __restrict__ nsyn,
                                             const unsigned* __restrict__ mskip,
                                             const int* __restrict__ sidx,
                                             const int* __restrict__ ridx,
                                             const float* __restrict__ rval,
                                             const float* __restrict__ grad,
                                             const unsigned* __restrict__ hcnt,
                                             unsigned* __restrict__ mout){
  unsigned Un = 0u, M = 0u;
  if (MODE == 1 || MODE == 2){
    Un = nsyn[0];
    M = mskip[0];
    if ((unsigned)blockIdx.x * TILE >= Un && M <= Un) return;
  }
  __shared__ unsigned wrun[4*256];
  __shared__ unsigned gput[256];
  __shared__ unsigned lw[4];
  __shared__ unsigned cutm;
  __shared__ uint64_t stage[TILE];       // 32 KB
  unsigned t = threadIdx.x, lane = t & 63u, w = t >> 6;
  wrun[t] = 0; wrun[256+t] = 0; wrun[512+t] = 0; wrun[768+t] = 0;
  __syncthreads();
  uint64_t ltm = (lane == 0) ? 0ull : (~0ull >> (64u - lane));
  uint64_t elems[WPT]; unsigned rnk[WPT]; unsigned dg[WPT];
  size_t base = (size_t)blockIdx.x * TILE + (size_t)w * (TILE/4);
  #pragma unroll
  for (int r = 0; r < WPT; r++){
    unsigned idx = (unsigned)(base + (size_t)r*64) + lane;
    uint64_t e;
    if (MODE == 3){
      e = make_elem(idx, sidx, ridx, rval, grad);
    } else if (MODE == 4){
      unsigned cnt = hcnt[blockIdx.x * 16u + (w << 2) + ((unsigned)r >> 2)];
      unsigned sl  = (((unsigned)r & 3u) << 6) + lane;
      e = (sl < cnt) ? in[idx] : SENT;
    } else if (MODE != 0){
      e = (idx < Un) ? in[idx] : SENT;
    } else {
      e = in[idx];
    }
    elems[r] = e;
    unsigned d = (unsigned)((e >> shift) & 0xFF);
    uint64_t m = ~0ull;
    #pragma unroll
    for (int b = 0; b < 8; b++){
      uint64_t bb = __ballot((d >> b) & 1u);
      m &= ((d >> b) & 1u) ? bb : ~bb;
    }
    unsigned rr   = (unsigned)__popcll(m & ltm);
    unsigned prev = wrun[w*256 + d];
    __builtin_amdgcn_wave_barrier();
    if (rr == 0) wrun[w*256 + d] = prev + (unsigned)__popcll(m);
    __builtin_amdgcn_wave_barrier();
    rnk[r] = prev + rr;
    dg[r]  = d;
  }
  __syncthreads();
  {
    unsigned d = t;
    unsigned c0 = wrun[d], c1 = wrun[256+d], c2 = wrun[512+d], c3 = wrun[768+d];
    unsigned cnt = c0 + c1 + c2 + c3;
    unsigned tot;
    unsigned ldig  = blockScanExcl(cnt, t, lw, &tot);       // local digit start
    unsigned tot2;
    unsigned dbase = blockScanExcl(dtot[d], t, lw, &tot2);  // global digit base
    if (MODE == 4){
      unsigned incl = dbase + dtot[d];                      // == k_cut arithmetic
      if (dbase < R_N && incl >= R_N) cutm = incl;
    }
    gput[d] = dbase + gh[d * NTILES + blockIdx.x] - ldig;
    wrun[d]       = ldig;
    wrun[256 + d] = ldig + c0;
    wrun[512 + d] = ldig + c0 + c1;
    wrun[768 + d] = ldig + c0 + c1 + c2;
  }
  __syncthreads();
  if (MODE == 4){
    M = cutm;
    if (blockIdx.x == 0u && t == 0u) mout[0] = M;           // for later kernels
  }
  #pragma unroll
  for (int r = 0; r < WPT; r++)
    stage[ wrun[w*256 + dg[r]] + rnk[r] ] = elems[r];
  __syncthreads();
  #pragma unroll
  for (int r = 0; r < WPT; r++){
    unsigned j = (unsigned)r * 256u + t;
    uint64_t e = stage[j];
    unsigned d = (unsigned)((e >> shift) & 0xFF);
    unsigned dest = gput[d] + j;
    if (MODE == 2){
      if (dest < R_N){
        uint32_t key = (uint32_t)(e >> 32);
        fout[2u*dest]        = (float)(key >> 12);
        fout[2u*dest + 1u]   = (float)(key & 4095u);
        fout[2u*R_N + dest]  = __uint_as_float(~(uint32_t)e);
      }
    } else if (MODE == 1 || MODE == 4){
      if (dest < M) out[dest] = e;
    } else {
      out[dest] = e;
    }
  }
}

__global__ __launch_bounds__(256) void k_scatter(const uint64_t* __restrict__ in,
                                                 uint64_t* __restrict__ out,
                                                 unsigned shift,
                                                 const unsigned* __restrict__ gh,
                                                 const unsigned* __restrict__ dtot){
  scatter_body<0>(in, out, nullptr, shift, gh, dtot, nullptr, nullptr,
                  nullptr, nullptr, nullptr, nullptr, nullptr, nullptr);
}

__global__ __launch_bounds__(256) void k_scatter_b(const int* __restrict__ sidx,
                                                   const int* __restrict__ ridx,
                                                   const float* __restrict__ rval,
                                                   const float* __restrict__ grad,
                                                   uint64_t* __restrict__ out,
                                                   unsigned shift,
                                                   const unsigned* __restrict__ gh,
                                                   const unsigned* __restrict__ dtot){
  scatter_body<3>(nullptr, out, nullptr, shift, gh, dtot, nullptr, nullptr,
                  sidx, ridx, rval, grad, nullptr, nullptr);
}

__global__ __launch_bounds__(256) void k_scatter_m(const uint64_t* __restrict__ in,
                                                   uint64_t* __restrict__ out,
                                                   unsigned shift,
                                                   const unsigned* __restrict__ gh,
                                                   const unsigned* __restrict__ dtot,
                                                   const unsigned* __restrict__ nsyn,
                                                   const unsigned* __restrict__ mskip){
  scatter_body<1>(in, out, nullptr, shift, gh, dtot, nsyn, mskip,
                  nullptr, nullptr, nullptr, nullptr, nullptr, nullptr);
}

__global__ __launch_bounds__(256) void k_scatter_mg(const uint64_t* __restrict__ in,
                                                    uint64_t* __restrict__ out,
                                                    unsigned shift,
                                                    const unsigned* __restrict__ gh,
                                                    const unsigned* __restrict__ dtot,
                                                    const unsigned* __restrict__ hcnt,
                                                    unsigned* __restrict__ mout){
  scatter_body<4>(in, out, nullptr, shift, gh, dtot, nullptr, nullptr,
                  nullptr, nullptr, nullptr, nullptr, hcnt, mout);
}

__global__ __launch_bounds__(256) void k_scatter_out(const uint64_t* __restrict__ in,
                                                     float* __restrict__ fout,
                                                     unsigned shift,
                                                     const unsigned* __restrict__ gh,
                                                     const unsigned* __restrict__ dtot,
                                                     const unsigned* __restrict__ nsyn){
  scatter_body<2>(in, nullptr, fout, shift, gh, dtot, nsyn, nsyn,
                  nullptr, nullptr, nullptr, nullptr, nullptr, nullptr);
}

// In-order segmented sum, GAPPED OUTPUT: one thread per element (proven shape;
// TLP hides the serial walks). Each block writes its candidates densely into
// its OWN 256-slot region out[b*256 + rank] and records hcnt[b] = count.
// Candidate order (block asc, rank asc) remains globally key-ascending.
__global__ __launch_bounds__(256) void k_segsum2(const uint64_t* __restrict__ in,
                                                 uint64_t* __restrict__ out,
                                                 unsigned* __restrict__ hcnt){
  __shared__ unsigned wc[4], woffs[4];
  unsigned t = threadIdx.x, lane = t & 63u, w = t >> 6;
  size_t p = (size_t)blockIdx.x * 256 + t;
  uint64_t e0 = in[p];
  uint32_t k = (uint32_t)(e0 >> 32);
  bool head = ((p == 0) || ((uint32_t)(in[p-1] >> 32) != k)) && ((uint32_t)e0 != PAD_VAL);
  uint64_t m = __ballot(head);
  if (lane == 0) wc[w] = (unsigned)__popcll(m);
  __syncthreads();
  if (t == 0){
    unsigned a = 0;
    for (int i = 0; i < 4; i++){ woffs[i] = a; a += wc[i]; }
    hcnt[blockIdx.x] = a;
  }
  __syncthreads();
  if (head){
    uint64_t ltm = (lane == 0) ? 0ull : (~0ull >> (64u - lane));
    unsigned rank = (unsigned)__popcll(m & ltm);
    unsigned oidx = blockIdx.x * 256u + woffs[w] + rank;
    float s = __uint_as_float((uint32_t)e0);
    size_t q = p + 1;
    while (q < NPAD){
      uint64_t e = in[q];
      if ((uint32_t)(e >> 32) != k) break;
      uint32_t vb = (uint32_t)e;
      if (vb == PAD_VAL) break;
      s += __uint_as_float(vb);
      q++;
    }
    out[oidx] = ((uint64_t)k << 32) | (uint64_t)(uint32_t)(~__float_as_uint(s));
  }
}

extern "C" void kernel_launch(void* const* d_in, const int* in_sizes, int n_in,
                              void* d_out, int out_size, void* d_ws, size_t ws_size,
                              hipStream_t stream) {
  const int*   sidx = (const int*)d_in[0];
  const int*   ridx = (const int*)d_in[1];
  const float* rval = (const float*)d_in[2];
  const float* grad = (const float*)d_in[3];
  float* out = (float*)d_out;

  uint64_t* A0   = (uint64_t*)d_ws;                       // 35.3 MB
  uint64_t* A1   = A0 + NPAD;                             // 35.3 MB
  unsigned* gh   = (unsigned*)(A1 + NPAD);                // 1.1 MB
  unsigned* dtot = gh + 256 * NTILES;                     // 1 KB
  unsigned* hcnt = dtot + 256;                            // 67 KB
  unsigned* mvar = hcnt + NSB;                            // 4 B
  unsigned* dcnt = mvar + 1;                              // 32 B (8 tickets)

  // Zero ticket counters (workspace re-poisoned each run).
  k_zero<<<1, 64, 0, stream>>>(dcnt);

  // Stable key sort: 24 bits, 3 x 8-bit passes. Pass 1 recomputes elements
  // from the raw inputs. Each hist+scan is ONE fused dispatch.
  k_histscan<0><<<NTILES, 256, 0, stream>>>(nullptr, sidx, ridx, 0, gh, dtot, nullptr, dcnt + 0);
  k_scatter_b  <<<NTILES, 256, 0, stream>>>(sidx, ridx, rval, grad, A1, 32, gh, dtot);
  k_histscan<1><<<NTILES, 256, 0, stream>>>(A1, nullptr, nullptr, 40, gh, dtot, nullptr, dcnt + 1);
  k_scatter    <<<NTILES, 256, 0, stream>>>(A1, A0, 40, gh, dtot);
  k_histscan<1><<<NTILES, 256, 0, stream>>>(A0, nullptr, nullptr, 48, gh, dtot, nullptr, dcnt + 2);
  k_scatter    <<<NTILES, 256, 0, stream>>>(A0, A1, 48, gh, dtot);

  // Coalesce, gapped: per-256-block dense candidates + hcnt.
  k_segsum2<<<NSB, 256, 0, stream>>>(A1, A0, hcnt);

  // Select: gapped byte-24 hist+scan fused, then gapped compact scatter with
  // fused cut (M persisted to mvar). Output A1[0, M) is dense.
  k_histscan<3><<<NTILES, 256, 0, stream>>>(A0, nullptr, nullptr, 24, gh, dtot, hcnt, dcnt + 3);
  k_scatter_mg <<<NTILES, 256, 0, stream>>>(A0, A1, 24, gh, dtot, hcnt, mvar);

  // Stable value sort over only M elements: 4 x 8-bit LSD passes,
  // final pass fused with output emission. A1->A0->A1->A0->out.
  k_histscan<2><<<NTILES, 256, 0, stream>>>(A1, nullptr, nullptr, 0, gh, dtot, mvar, dcnt + 4);
  k_scatter_m  <<<NTILES, 256, 0, stream>>>(A1, A0, 0, gh, dtot, mvar, mvar);
  k_histscan<2><<<NTILES, 256, 0, stream>>>(A0, nullptr, nullptr, 8, gh, dtot, mvar, dcnt + 5);
  k_scatter_m  <<<NTILES, 256, 0, stream>>>(A0, A1, 8, gh, dtot, mvar, mvar);
  k_histscan<2><<<NTILES, 256, 0, stream>>>(A1, nullptr, nullptr, 16, gh, dtot, mvar, dcnt + 6);
  k_scatter_m  <<<NTILES, 256, 0, stream>>>(A1, A0, 16, gh, dtot, mvar, mvar);
  k_histscan<2><<<NTILES, 256, 0, stream>>>(A0, nullptr, nullptr, 24, gh, dtot, mvar, dcnt + 7);
  k_scatter_out<<<NTILES, 256, 0, stream>>>(A0, out, 24, gh, dtot, mvar);
}

// Round 11
// 400.305 us; speedup vs baseline: 4.9547x; 4.9547x over previous
//
#include <hip/hip_runtime.h>
#include <stdint.h>

#define CDIM   4096
#define S_N    3355443
#define R_N    1048576
#define N1     (S_N + R_N)                 // 4404019 contributions
#define TILE   4096
#define WPT    (TILE / 256)                // 16 elements per thread
#define NTILES ((N1 + TILE - 1) / TILE)    // 1076
#define NPAD   (NTILES * TILE)             // 4407296
#define NSB    (NPAD / 256)                // 17216 (== NTILES*16)
#define SR_CH  ((NTILES + 255) / 256)      // 5 row entries per thread in scanrows
#define SW_CH  ((NSB + 255) / 256)         // 68 row entries per thread in scanrows_w
#define PAD_KEY 0xFFFFFFu
#define PAD_VAL 0xFFFFFFFFu                // impossible value bits (sums are >= +0)
#define SENT  (((uint64_t)PAD_KEY << 32) | (uint64_t)PAD_VAL)
#define ADJF  ((float)(1.0 - (3355443.0 / 16777216.0) * (1.0 - 0.95)))

// Exclusive block-wide scan over 256 threads (4 waves). Contains syncthreads.
static __device__ __forceinline__ unsigned blockScanExcl(unsigned v, unsigned t,
                                                         unsigned* lw, unsigned* tot){
  unsigned lane = t & 63u, w = t >> 6;
  unsigned x = v;
  #pragma unroll
  for (int off = 1; off < 64; off <<= 1){
    unsigned y = __shfl_up(x, off, 64);
    if (lane >= (unsigned)off) x += y;
  }
  if (lane == 63u) lw[w] = x;
  __syncthreads();
  unsigned woff = 0;
  for (unsigned i = 0; i < w; i++) woff += lw[i];
  *tot = lw[0] + lw[1] + lw[2] + lw[3];
  __syncthreads();
  return x + woff - v;
}

// Recompute element i of the contribution array from the raw inputs.
// Samples first, then decayed buffer entries, then padding -> stable sort
// preserves segment_sum's accumulation order exactly.
static __device__ __forceinline__ uint64_t make_elem(unsigned i,
                                                     const int* __restrict__ sidx,
                                                     const int* __restrict__ ridx,
                                                     const float* __restrict__ rval,
                                                     const float* __restrict__ grad){
  uint32_t key, vb;
  if (i < S_N){
    key = (uint32_t)sidx[i];
    vb  = __float_as_uint(fabsf(grad[i]));
  } else if (i < N1){
    unsigned j = i - S_N;
    int2 rc = ((const int2* __restrict__)ridx)[j];
    key = (uint32_t)(rc.x * CDIM + rc.y);
    vb = __float_as_uint(ADJF * rval[j]);
  } else {
    key = PAD_KEY; vb = PAD_VAL;
  }
  return ((uint64_t)key << 32) | (uint64_t)vb;
}

// Pass-1 key histogram straight from the inputs (key low byte only: needs
// sidx + ridx.y, NOT grad/rval, and writes no element array).
__global__ __launch_bounds__(256) void k_hist0(const int* __restrict__ sidx,
                                               const int* __restrict__ ridx,
                                               unsigned* __restrict__ gh){
  __shared__ unsigned h[256];
  unsigned t = threadIdx.x, b = blockIdx.x;
  h[t] = 0; __syncthreads();
  size_t base = (size_t)b * TILE;
  #pragma unroll
  for (int r = 0; r < WPT; r++){
    unsigned i = (unsigned)(base + (size_t)r*256 + t);
    unsigned kb;
    if (i < S_N)       kb = ((uint32_t)sidx[i]) & 0xFFu;
    else if (i < N1)   kb = ((uint32_t)ridx[2u*(i - S_N) + 1u]) & 0xFFu; // col low byte
    else               kb = 0xFFu;                                       // PAD_KEY & 0xFF
    atomicAdd(&h[kb], 1u);         // LDS atomic only
  }
  __syncthreads();
  gh[t * NTILES + b] = h[t];
}

// Per-tile 256-bin histogram of digit (e >> shift) & 0xFF. Layout [digit][tile].
__global__ __launch_bounds__(256) void k_hist(const uint64_t* __restrict__ in, unsigned shift,
                                              unsigned* __restrict__ gh){
  __shared__ unsigned h[256];
  unsigned t = threadIdx.x;
  h[t] = 0; __syncthreads();
  size_t base = (size_t)blockIdx.x * TILE;
  #pragma unroll
  for (int r = 0; r < WPT; r++){
    uint64_t e = in[base + (size_t)r*256 + t];
    atomicAdd(&h[(unsigned)((e >> shift) & 0xFF)], 1u);
  }
  __syncthreads();
  gh[t * NTILES + blockIdx.x] = h[t];
}

// Histogram over the DENSE prefix [0, nsyn[0]) with sentinel synthesis beyond
// it. Tail tiles write their (constant) column and return.
__global__ __launch_bounds__(256) void k_hist_syn(const uint64_t* __restrict__ in, unsigned shift,
                                                  unsigned* __restrict__ gh,
                                                  const unsigned* __restrict__ nsyn){
  __shared__ unsigned h[256];
  unsigned t = threadIdx.x;
  unsigned Un = nsyn[0];
  size_t base = (size_t)blockIdx.x * TILE;
  if (base >= (size_t)Un){
    gh[t * NTILES + blockIdx.x] = (t == 255u) ? (unsigned)TILE : 0u;
    return;
  }
  h[t] = 0; __syncthreads();
  #pragma unroll
  for (int r = 0; r < WPT; r++){
    unsigned i = (unsigned)(base + (size_t)r*256 + t);
    uint64_t e = (i < Un) ? in[i] : SENT;
    atomicAdd(&h[(unsigned)((e >> shift) & 0xFF)], 1u);
  }
  __syncthreads();
  gh[t * NTILES + blockIdx.x] = h[t];
}

// Row scan: block d turns gh[d][*] into exclusive tile prefixes + digit total.
// Blocked per-thread ownership + ONE blockScan (2 syncthreads instead of 10).
__global__ __launch_bounds__(256) void k_scanrows(unsigned* __restrict__ gh,
                                                  unsigned* __restrict__ dtot){
  __shared__ unsigned lw[4];
  unsigned d = blockIdx.x, t = threadIdx.x;
  unsigned rowbase = d * NTILES;
  unsigned vals[SR_CH];
  unsigned s = 0;
  #pragma unroll
  for (int k = 0; k < SR_CH; k++){
    unsigned i = t * SR_CH + (unsigned)k;
    vals[k] = (i < NTILES) ? gh[rowbase + i] : 0u;
    s += vals[k];
  }
  unsigned tot;
  unsigned carry = blockScanExcl(s, t, lw, &tot);
  #pragma unroll
  for (int k = 0; k < SR_CH; k++){
    unsigned i = t * SR_CH + (unsigned)k;
    if (i < NTILES){ gh[rowbase + i] = carry; carry += vals[k]; }
  }
  if (t == 0) dtot[d] = tot;
}

// Wide row scan for the fused select hist: row d of ghw is NSB u16 sub-block
// counts (written by k_segsum2). Scans the row and emits ONLY tile-granular
// (every 16th) prefixes into the u32 gh matrix + dtot -> scatter_mg consumes
// the exact same format as before. Same LDS-staging shape as the proven
// k_scanheads (u16 buf, blocked 68/thread, one blockScan).
__global__ __launch_bounds__(256) void k_scanrows_w(const unsigned short* __restrict__ ghw,
                                                    unsigned* __restrict__ gh,
                                                    unsigned* __restrict__ dtot){
  __shared__ unsigned short buf[NSB];    // 34.4 KB
  __shared__ unsigned lw[4];
  unsigned d = blockIdx.x, t = threadIdx.x;
  for (unsigned i = t; i < NSB; i += 256) buf[i] = ghw[(size_t)d * NSB + i];
  __syncthreads();
  unsigned s = 0;
  for (unsigned k = 0; k < SW_CH; k++){
    unsigned i = t * SW_CH + k;
    if (i < NSB) s += (unsigned)buf[i];
  }
  unsigned tot;
  unsigned carry = blockScanExcl(s, t, lw, &tot);
  for (unsigned k = 0; k < SW_CH; k++){
    unsigned i = t * SW_CH + k;
    if (i < NSB){
      if ((i & 15u) == 0u) gh[d * NTILES + (i >> 4)] = carry;
      carry += (unsigned)buf[i];
    }
  }
  if (t == 0) dtot[d] = tot;
}

// ---- LDS-staged stable radix scatter (unchanged from round 9) -------------
// MODE 0: plain pass over the full NPAD array.
// MODE 1: M-mode (value LSD over dense [0,M)): synthesize SENT for
//         i >= nsyn[0]; write only dest < mskip[0].
// MODE 2: M-mode final: emit output rows for dest < R_N.
// MODE 3: build-recompute: elements recomputed from raw inputs (key pass 1).
// MODE 4: GAPPED compact with FUSED CUT: element validity from hcnt[sb]
//         (prefix of each 256-slot sub-block); M computed in phase B from the
//         dtot scan (identical arithmetic to a standalone k_cut); block 0
//         persists mvar. Sentinels land in bin 255 which is always >= M, so
//         none is ever written and kept-element placement is unchanged.
template <int MODE>
__device__ __forceinline__ void scatter_body(const uint64_t* __restrict__ in,
                                             uint64_t* __restrict__ out,
                                             float* __restrict__ fout,
                                             unsigned shift,
                                             const unsigned* __restrict__ gh,
                                             const unsigned* __restrict__ dtot,
                                             const unsigned* __restrict__ nsyn,
                                             const unsigned* __restrict__ mskip,
                                             const int* __restrict__ sidx,
                                             const int* __restrict__ ridx,
                                             const float* __restrict__ rval,
                                             const float* __restrict__ grad,
                                             const unsigned* __restrict__ hcnt,
                                             unsigned* __restrict__ mout){
  unsigned Un = 0u, M = 0u;
  if (MODE == 1 || MODE == 2){
    Un = nsyn[0];
    M = mskip[0];
    if ((unsigned)blockIdx.x * TILE >= Un && M <= Un) return;
  }
  __shared__ unsigned wrun[4*256];
  __shared__ unsigned gput[256];
  __shared__ unsigned lw[4];
  __shared__ unsigned cutm;
  __shared__ uint64_t stage[TILE];       // 32 KB
  unsigned t = threadIdx.x, lane = t & 63u, w = t >> 6;
  wrun[t] = 0; wrun[256+t] = 0; wrun[512+t] = 0; wrun[768+t] = 0;
  __syncthreads();
  uint64_t ltm = (lane == 0) ? 0ull : (~0ull >> (64u - lane));
  uint64_t elems[WPT]; unsigned rnk[WPT]; unsigned dg[WPT];
  size_t base = (size_t)blockIdx.x * TILE + (size_t)w * (TILE/4);
  #pragma unroll
  for (int r = 0; r < WPT; r++){
    unsigned idx = (unsigned)(base + (size_t)r*64) + lane;
    uint64_t e;
    if (MODE == 3){
      e = make_elem(idx, sidx, ridx, rval, grad);
    } else if (MODE == 4){
      unsigned cnt = hcnt[blockIdx.x * 16u + (w << 2) + ((unsigned)r >> 2)];
      unsigned sl  = (((unsigned)r & 3u) << 6) + lane;
      e = (sl < cnt) ? in[idx] : SENT;
    } else if (MODE != 0){
      e = (idx < Un) ? in[idx] : SENT;
    } else {
      e = in[idx];
    }
    elems[r] = e;
    unsigned d = (unsigned)((e >> shift) & 0xFF);
    uint64_t m = ~0ull;
    #pragma unroll
    for (int b = 0; b < 8; b++){
      uint64_t bb = __ballot((d >> b) & 1u);
      m &= ((d >> b) & 1u) ? bb : ~bb;
    }
    unsigned rr   = (unsigned)__popcll(m & ltm);
    unsigned prev = wrun[w*256 + d];
    __builtin_amdgcn_wave_barrier();
    if (rr == 0) wrun[w*256 + d] = prev + (unsigned)__popcll(m);
    __builtin_amdgcn_wave_barrier();
    rnk[r] = prev + rr;
    dg[r]  = d;
  }
  __syncthreads();
  {
    unsigned d = t;
    unsigned c0 = wrun[d], c1 = wrun[256+d], c2 = wrun[512+d], c3 = wrun[768+d];
    unsigned cnt = c0 + c1 + c2 + c3;
    unsigned tot;
    unsigned ldig  = blockScanExcl(cnt, t, lw, &tot);       // local digit start
    unsigned tot2;
    unsigned dbase = blockScanExcl(dtot[d], t, lw, &tot2);  // global digit base
    if (MODE == 4){
      unsigned incl = dbase + dtot[d];                      // == k_cut arithmetic
      if (dbase < R_N && incl >= R_N) cutm = incl;
    }
    gput[d] = dbase + gh[d * NTILES + blockIdx.x] - ldig;
    wrun[d]       = ldig;
    wrun[256 + d] = ldig + c0;
    wrun[512 + d] = ldig + c0 + c1;
    wrun[768 + d] = ldig + c0 + c1 + c2;
  }
  __syncthreads();
  if (MODE == 4){
    M = cutm;
    if (blockIdx.x == 0u && t == 0u) mout[0] = M;           // for later kernels
  }
  #pragma unroll
  for (int r = 0; r < WPT; r++)
    stage[ wrun[w*256 + dg[r]] + rnk[r] ] = elems[r];
  __syncthreads();
  #pragma unroll
  for (int r = 0; r < WPT; r++){
    unsigned j = (unsigned)r * 256u + t;
    uint64_t e = stage[j];
    unsigned d = (unsigned)((e >> shift) & 0xFF);
    unsigned dest = gput[d] + j;
    if (MODE == 2){
      if (dest < R_N){
        uint32_t key = (uint32_t)(e >> 32);
        fout[2u*dest]        = (float)(key >> 12);
        fout[2u*dest + 1u]   = (float)(key & 4095u);
        fout[2u*R_N + dest]  = __uint_as_float(~(uint32_t)e);
      }
    } else if (MODE == 1 || MODE == 4){
      if (dest < M) out[dest] = e;
    } else {
      out[dest] = e;
    }
  }
}

__global__ __launch_bounds__(256) void k_scatter(const uint64_t* __restrict__ in,
                                                 uint64_t* __restrict__ out,
                                                 unsigned shift,
                                                 const unsigned* __restrict__ gh,
                                                 const unsigned* __restrict__ dtot){
  scatter_body<0>(in, out, nullptr, shift, gh, dtot, nullptr, nullptr,
                  nullptr, nullptr, nullptr, nullptr, nullptr, nullptr);
}

__global__ __launch_bounds__(256) void k_scatter_b(const int* __restrict__ sidx,
                                                   const int* __restrict__ ridx,
                                                   const float* __restrict__ rval,
                                                   const float* __restrict__ grad,
                                                   uint64_t* __restrict__ out,
                                                   unsigned shift,
                                                   const unsigned* __restrict__ gh,
                                                   const unsigned* __restrict__ dtot){
  scatter_body<3>(nullptr, out, nullptr, shift, gh, dtot, nullptr, nullptr,
                  sidx, ridx, rval, grad, nullptr, nullptr);
}

__global__ __launch_bounds__(256) void k_scatter_m(const uint64_t* __restrict__ in,
                                                   uint64_t* __restrict__ out,
                                                   unsigned shift,
                                                   const unsigned* __restrict__ gh,
                                                   const unsigned* __restrict__ dtot,
                                                   const unsigned* __restrict__ nsyn,
                                                   const unsigned* __restrict__ mskip){
  scatter_body<1>(in, out, nullptr, shift, gh, dtot, nsyn, mskip,
                  nullptr, nullptr, nullptr, nullptr, nullptr, nullptr);
}

__global__ __launch_bounds__(256) void k_scatter_mg(const uint64_t* __restrict__ in,
                                                    uint64_t* __restrict__ out,
                                                    unsigned shift,
                                                    const unsigned* __restrict__ gh,
                                                    const unsigned* __restrict__ dtot,
                                                    const unsigned* __restrict__ hcnt,
                                                    unsigned* __restrict__ mout){
  scatter_body<4>(in, out, nullptr, shift, gh, dtot, nullptr, nullptr,
                  nullptr, nullptr, nullptr, nullptr, hcnt, mout);
}

__global__ __launch_bounds__(256) void k_scatter_out(const uint64_t* __restrict__ in,
                                                     float* __restrict__ fout,
                                                     unsigned shift,
                                                     const unsigned* __restrict__ gh,
                                                     const unsigned* __restrict__ dtot,
                                                     const unsigned* __restrict__ nsyn){
  scatter_body<2>(in, nullptr, fout, shift, gh, dtot, nsyn, nsyn,
                  nullptr, nullptr, nullptr, nullptr, nullptr, nullptr);
}

// In-order segmented sum, GAPPED OUTPUT: one thread per element (proven shape;
// TLP hides the serial walks). Each block writes its candidates densely into
// its OWN 256-slot region out[b*256 + rank] and records hcnt[b] = count.
// Candidate order (block asc, rank asc) remains globally key-ascending.
// FUSED (zero-sync, block-local): byte-24 histogram of this block's
// candidates + (256-count) sentinels in bin 255, written as a u16 column to
// ghw[digit][b] -> replaces the separate k_hist_syn2 full-array pass.
__global__ __launch_bounds__(256) void k_segsum2(const uint64_t* __restrict__ in,
                                                 uint64_t* __restrict__ out,
                                                 unsigned* __restrict__ hcnt,
                                                 unsigned short* __restrict__ ghw){
  __shared__ unsigned wc[4], woffs[4];
  __shared__ unsigned h[256];
  __shared__ unsigned acount;
  unsigned t = threadIdx.x, lane = t & 63u, w = t >> 6;
  unsigned b = blockIdx.x;
  h[t] = 0;
  size_t p = (size_t)b * 256 + t;
  uint64_t e0 = in[p];
  uint32_t k = (uint32_t)(e0 >> 32);
  bool head = ((p == 0) || ((uint32_t)(in[p-1] >> 32) != k)) && ((uint32_t)e0 != PAD_VAL);
  uint64_t m = __ballot(head);
  if (lane == 0) wc[w] = (unsigned)__popcll(m);
  __syncthreads();
  if (t == 0){
    unsigned a = 0;
    for (int i = 0; i < 4; i++){ woffs[i] = a; a += wc[i]; }
    hcnt[b] = a;
    acount = a;
  }
  __syncthreads();
  if (head){
    uint64_t ltm = (lane == 0) ? 0ull : (~0ull >> (64u - lane));
    unsigned rank = (unsigned)__popcll(m & ltm);
    unsigned oidx = b * 256u + woffs[w] + rank;
    float s = __uint_as_float((uint32_t)e0);
    size_t q = p + 1;
    while (q < NPAD){
      uint64_t e = in[q];
      if ((uint32_t)(e >> 32) != k) break;
      uint32_t vb = (uint32_t)e;
      if (vb == PAD_VAL) break;
      s += __uint_as_float(vb);
      q++;
    }
    uint32_t ov = ~__float_as_uint(s);
    out[oidx] = ((uint64_t)k << 32) | (uint64_t)ov;
    atomicAdd(&h[(ov >> 24) & 0xFFu], 1u);      // LDS atomic only
  }
  __syncthreads();
  unsigned v = h[t] + ((t == 255u) ? (256u - acount) : 0u);  // sentinel slots
  ghw[(size_t)t * NSB + b] = (unsigned short)v;
}

extern "C" void kernel_launch(void* const* d_in, const int* in_sizes, int n_in,
                              void* d_out, int out_size, void* d_ws, size_t ws_size,
                              hipStream_t stream) {
  const int*   sidx = (const int*)d_in[0];
  const int*   ridx = (const int*)d_in[1];
  const float* rval = (const float*)d_in[2];
  const float* grad = (const float*)d_in[3];
  float* out = (float*)d_out;

  uint64_t* A0   = (uint64_t*)d_ws;                       // 35.3 MB
  uint64_t* A1   = A0 + NPAD;                             // 35.3 MB
  unsigned* gh   = (unsigned*)(A1 + NPAD);                // 1.1 MB
  unsigned* dtot = gh + 256 * NTILES;                     // 1 KB
  unsigned* hcnt = dtot + 256;                            // 67 KB
  unsigned* mvar = hcnt + NSB;                            // 4 B
  unsigned short* ghw = (unsigned short*)(mvar + 1);      // 8.8 MB (u16 [256][NSB])

  // Stable key sort: 24 bits, 3 x 8-bit passes. Pass 1 recomputes elements
  // from the raw inputs (no element-array build/read). inputs->A1->A0->A1.
  k_hist0    <<<NTILES, 256, 0, stream>>>(sidx, ridx, gh);
  k_scanrows <<<256,    256, 0, stream>>>(gh, dtot);
  k_scatter_b<<<NTILES, 256, 0, stream>>>(sidx, ridx, rval, grad, A1, 32, gh, dtot);
  k_hist     <<<NTILES, 256, 0, stream>>>(A1, 40, gh);
  k_scanrows <<<256,    256, 0, stream>>>(gh, dtot);
  k_scatter  <<<NTILES, 256, 0, stream>>>(A1, A0, 40, gh, dtot);
  k_hist     <<<NTILES, 256, 0, stream>>>(A0, 48, gh);
  k_scanrows <<<256,    256, 0, stream>>>(gh, dtot);
  k_scatter  <<<NTILES, 256, 0, stream>>>(A0, A1, 48, gh, dtot);

  // Coalesce, gapped: per-256-block dense candidates + hcnt + FUSED byte-24
  // sub-block hist columns (replaces the k_hist_syn2 full-array read).
  k_segsum2<<<NSB, 256, 0, stream>>>(A1, A0, hcnt, ghw);

  // Select: wide row scan of the fused hist -> tile-granular gh + dtot
  // (identical format/values to round 9), then gapped compact scatter with
  // fused cut (M persisted to mvar). Output A1[0, M) is dense.
  k_scanrows_w<<<256,    256, 0, stream>>>(ghw, gh, dtot);
  k_scatter_mg<<<NTILES, 256, 0, stream>>>(A0, A1, 24, gh, dtot, hcnt, mvar);

  // Stable value sort over only M elements: 4 x 8-bit LSD passes,
  // final pass fused with output emission. A1->A0->A1->A0->out.
  k_hist_syn <<<NTILES, 256, 0, stream>>>(A1, 0, gh, mvar);
  k_scanrows <<<256,    256, 0, stream>>>(gh, dtot);
  k_scatter_m<<<NTILES, 256, 0, stream>>>(A1, A0, 0, gh, dtot, mvar, mvar);
  k_hist_syn <<<NTILES, 256, 0, stream>>>(A0, 8, gh, mvar);
  k_scanrows <<<256,    256, 0, stream>>>(gh, dtot);
  k_scatter_m<<<NTILES, 256, 0, stream>>>(A0, A1, 8, gh, dtot, mvar, mvar);
  k_hist_syn <<<NTILES, 256, 0, stream>>>(A1, 16, gh, mvar);
  k_scanrows <<<256,    256, 0, stream>>>(gh, dtot);
  k_scatter_m<<<NTILES, 256, 0, stream>>>(A1, A0, 16, gh, dtot, mvar, mvar);
  k_hist_syn   <<<NTILES, 256, 0, stream>>>(A0, 24, gh, mvar);
  k_scanrows   <<<256,    256, 0, stream>>>(gh, dtot);
  k_scatter_out<<<NTILES, 256, 0, stream>>>(A0, out, 24, gh, dtot, mvar);
}

// Round 12
// 383.987 us; speedup vs baseline: 5.1653x; 1.0425x over previous
//
#include <hip/hip_runtime.h>
#include <stdint.h>

#define CDIM   4096
#define S_N    3355443
#define R_N    1048576
#define N1     (S_N + R_N)                 // 4404019 contributions
#define TILE   4096
#define WPT    (TILE / 256)                // 16 elements per thread
#define NTILES ((N1 + TILE - 1) / TILE)    // 1076
#define NPAD   (NTILES * TILE)             // 4407296
#define NSB    (NPAD / 256)                // 17216 (== NTILES*16)
#define SR_CH  ((NTILES + 255) / 256)      // 5 row entries per thread in scanrows
#define PAD_KEY 0xFFFFFFu
#define PAD_VAL 0xFFFFFFFFu                // impossible value bits (sums are >= +0)
#define SENT  (((uint64_t)PAD_KEY << 32) | (uint64_t)PAD_VAL)
#define ADJF  ((float)(1.0 - (3355443.0 / 16777216.0) * (1.0 - 0.95)))

// Exclusive block-wide scan over 256 threads (4 waves). Contains syncthreads.
static __device__ __forceinline__ unsigned blockScanExcl(unsigned v, unsigned t,
                                                         unsigned* lw, unsigned* tot){
  unsigned lane = t & 63u, w = t >> 6;
  unsigned x = v;
  #pragma unroll
  for (int off = 1; off < 64; off <<= 1){
    unsigned y = __shfl_up(x, off, 64);
    if (lane >= (unsigned)off) x += y;
  }
  if (lane == 63u) lw[w] = x;
  __syncthreads();
  unsigned woff = 0;
  for (unsigned i = 0; i < w; i++) woff += lw[i];
  *tot = lw[0] + lw[1] + lw[2] + lw[3];
  __syncthreads();
  return x + woff - v;
}

// Recompute element i of the contribution array from the raw inputs.
// Samples first, then decayed buffer entries, then padding -> stable sort
// preserves segment_sum's accumulation order exactly.
static __device__ __forceinline__ uint64_t make_elem(unsigned i,
                                                     const int* __restrict__ sidx,
                                                     const int* __restrict__ ridx,
                                                     const float* __restrict__ rval,
                                                     const float* __restrict__ grad){
  uint32_t key, vb;
  if (i < S_N){
    key = (uint32_t)sidx[i];
    vb  = __float_as_uint(fabsf(grad[i]));
  } else if (i < N1){
    unsigned j = i - S_N;
    int2 rc = ((const int2* __restrict__)ridx)[j];
    key = (uint32_t)(rc.x * CDIM + rc.y);
    vb = __float_as_uint(ADJF * rval[j]);
  } else {
    key = PAD_KEY; vb = PAD_VAL;
  }
  return ((uint64_t)key << 32) | (uint64_t)vb;
}

// Pass-1 key histogram straight from the inputs (key low byte only: needs
// sidx + ridx.y, NOT grad/rval, and writes no element array).
__global__ __launch_bounds__(256) void k_hist0(const int* __restrict__ sidx,
                                               const int* __restrict__ ridx,
                                               unsigned* __restrict__ gh){
  __shared__ unsigned h[256];
  unsigned t = threadIdx.x, b = blockIdx.x;
  h[t] = 0; __syncthreads();
  size_t base = (size_t)b * TILE;
  #pragma unroll
  for (int r = 0; r < WPT; r++){
    unsigned i = (unsigned)(base + (size_t)r*256 + t);
    unsigned kb;
    if (i < S_N)       kb = ((uint32_t)sidx[i]) & 0xFFu;
    else if (i < N1)   kb = ((uint32_t)ridx[2u*(i - S_N) + 1u]) & 0xFFu; // col low byte
    else               kb = 0xFFu;                                       // PAD_KEY & 0xFF
    atomicAdd(&h[kb], 1u);         // LDS atomic only
  }
  __syncthreads();
  gh[t * NTILES + b] = h[t];
}

// Per-tile 256-bin histogram of digit (e >> shift) & 0xFF. Layout [digit][tile].
__global__ __launch_bounds__(256) void k_hist(const uint64_t* __restrict__ in, unsigned shift,
                                              unsigned* __restrict__ gh){
  __shared__ unsigned h[256];
  unsigned t = threadIdx.x;
  h[t] = 0; __syncthreads();
  size_t base = (size_t)blockIdx.x * TILE;
  #pragma unroll
  for (int r = 0; r < WPT; r++){
    uint64_t e = in[base + (size_t)r*256 + t];
    atomicAdd(&h[(unsigned)((e >> shift) & 0xFF)], 1u);
  }
  __syncthreads();
  gh[t * NTILES + blockIdx.x] = h[t];
}

// Histogram over the DENSE prefix [0, nsyn[0]) with sentinel synthesis beyond
// it. Tail tiles write their (constant) column and return.
__global__ __launch_bounds__(256) void k_hist_syn(const uint64_t* __restrict__ in, unsigned shift,
                                                  unsigned* __restrict__ gh,
                                                  const unsigned* __restrict__ nsyn){
  __shared__ unsigned h[256];
  unsigned t = threadIdx.x;
  unsigned Un = nsyn[0];
  size_t base = (size_t)blockIdx.x * TILE;
  if (base >= (size_t)Un){
    gh[t * NTILES + blockIdx.x] = (t == 255u) ? (unsigned)TILE : 0u;
    return;
  }
  h[t] = 0; __syncthreads();
  #pragma unroll
  for (int r = 0; r < WPT; r++){
    unsigned i = (unsigned)(base + (size_t)r*256 + t);
    uint64_t e = (i < Un) ? in[i] : SENT;
    atomicAdd(&h[(unsigned)((e >> shift) & 0xFF)], 1u);
  }
  __syncthreads();
  gh[t * NTILES + blockIdx.x] = h[t];
}

// Histogram over the GAPPED candidate layout: sub-block sb (256 slots) holds
// hcnt[sb] valid elements as a prefix; the rest are synthesized sentinels.
__global__ __launch_bounds__(256) void k_hist_syn2(const uint64_t* __restrict__ in, unsigned shift,
                                                   unsigned* __restrict__ gh,
                                                   const unsigned* __restrict__ hcnt){
  __shared__ unsigned h[256];
  unsigned t = threadIdx.x, b = blockIdx.x;
  h[t] = 0; __syncthreads();
  size_t base = (size_t)b * TILE;
  #pragma unroll
  for (int r = 0; r < WPT; r++){
    unsigned cnt = hcnt[b * 16u + (unsigned)r];
    uint64_t e = (t < cnt) ? in[base + (size_t)r*256 + t] : SENT;
    atomicAdd(&h[(unsigned)((e >> shift) & 0xFF)], 1u);
  }
  __syncthreads();
  gh[t * NTILES + b] = h[t];
}

// Row scan: block d turns gh[d][*] into exclusive tile prefixes + digit total.
// Blocked per-thread ownership + ONE blockScan (2 syncthreads instead of 10).
__global__ __launch_bounds__(256) void k_scanrows(unsigned* __restrict__ gh,
                                                  unsigned* __restrict__ dtot){
  __shared__ unsigned lw[4];
  unsigned d = blockIdx.x, t = threadIdx.x;
  unsigned rowbase = d * NTILES;
  unsigned vals[SR_CH];
  unsigned s = 0;
  #pragma unroll
  for (int k = 0; k < SR_CH; k++){
    unsigned i = t * SR_CH + (unsigned)k;
    vals[k] = (i < NTILES) ? gh[rowbase + i] : 0u;
    s += vals[k];
  }
  unsigned tot;
  unsigned carry = blockScanExcl(s, t, lw, &tot);
  #pragma unroll
  for (int k = 0; k < SR_CH; k++){
    unsigned i = t * SR_CH + (unsigned)k;
    if (i < NTILES){ gh[rowbase + i] = carry; carry += vals[k]; }
  }
  if (t == 0) dtot[d] = tot;
}

// ---- LDS-staged stable radix scatter -------------------------------------
// Phase A: per-wave stable ranks. Phase B: block digit scan -> bases.
// Phase C: stage tile in LDS ordered by (digit, pos). Phase D: coalesced
// runs per digit to global.
// MODE 0: plain pass over the full NPAD array.
// MODE 1: M-mode (value LSD over dense [0,M)): synthesize SENT for
//         i >= nsyn[0]; write only dest < mskip[0].
// MODE 2: M-mode final: emit output rows for dest < R_N.
// MODE 3: build-recompute: elements recomputed from raw inputs (key pass 1).
// MODE 4: GAPPED compact with FUSED CUT: element validity from hcnt[sb]
//         (prefix of each 256-slot sub-block); M computed in phase B from the
//         dtot scan (identical arithmetic to a standalone k_cut); block 0
//         persists mvar. Sentinels land in bin 255 which is always >= M, so
//         none is ever written and kept-element placement is unchanged.
template <int MODE>
__device__ __forceinline__ void scatter_body(const uint64_t* __restrict__ in,
                                             uint64_t* __restrict__ out,
                                             float* __restrict__ fout,
                                             unsigned shift,
                                             const unsigned* __restrict__ gh,
                                             const unsigned* __restrict__ dtot,
                                             const unsigned* __restrict__ nsyn,
                                             const unsigned* __restrict__ mskip,
                                             const int* __restrict__ sidx,
                                             const int* __restrict__ ridx,
                                             const float* __restrict__ rval,
                                             const float* __restrict__ grad,
                                             const unsigned* __restrict__ hcnt,
                                             unsigned* __restrict__ mout){
  unsigned Un = 0u, M = 0u;
  if (MODE == 1 || MODE == 2){
    Un = nsyn[0];
    M = mskip[0];
    if ((unsigned)blockIdx.x * TILE >= Un && M <= Un) return;
  }
  __shared__ unsigned wrun[4*256];
  __shared__ unsigned gput[256];
  __shared__ unsigned lw[4];
  __shared__ unsigned cutm;
  __shared__ uint64_t stage[TILE];       // 32 KB
  unsigned t = threadIdx.x, lane = t & 63u, w = t >> 6;
  wrun[t] = 0; wrun[256+t] = 0; wrun[512+t] = 0; wrun[768+t] = 0;
  __syncthreads();
  uint64_t ltm = (lane == 0) ? 0ull : (~0ull >> (64u - lane));
  uint64_t elems[WPT]; unsigned rnk[WPT]; unsigned dg[WPT];
  size_t base = (size_t)blockIdx.x * TILE + (size_t)w * (TILE/4);
  #pragma unroll
  for (int r = 0; r < WPT; r++){
    unsigned idx = (unsigned)(base + (size_t)r*64) + lane;
    uint64_t e;
    if (MODE == 3){
      e = make_elem(idx, sidx, ridx, rval, grad);
    } else if (MODE == 4){
      // sub-block within tile = w*4 + r/4; slot within sub-block = (r%4)*64+lane
      unsigned cnt = hcnt[blockIdx.x * 16u + (w << 2) + ((unsigned)r >> 2)];
      unsigned sl  = (((unsigned)r & 3u) << 6) + lane;
      e = (sl < cnt) ? in[idx] : SENT;
    } else if (MODE != 0){
      e = (idx < Un) ? in[idx] : SENT;
    } else {
      e = in[idx];
    }
    elems[r] = e;
    unsigned d = (unsigned)((e >> shift) & 0xFF);
    uint64_t m = ~0ull;
    #pragma unroll
    for (int b = 0; b < 8; b++){
      uint64_t bb = __ballot((d >> b) & 1u);
      m &= ((d >> b) & 1u) ? bb : ~bb;
    }
    unsigned rr   = (unsigned)__popcll(m & ltm);
    unsigned prev = wrun[w*256 + d];
    __builtin_amdgcn_wave_barrier();
    if (rr == 0) wrun[w*256 + d] = prev + (unsigned)__popcll(m);
    __builtin_amdgcn_wave_barrier();
    rnk[r] = prev + rr;
    dg[r]  = d;
  }
  __syncthreads();
  {
    unsigned d = t;
    unsigned c0 = wrun[d], c1 = wrun[256+d], c2 = wrun[512+d], c3 = wrun[768+d];
    unsigned cnt = c0 + c1 + c2 + c3;
    unsigned tot;
    unsigned ldig  = blockScanExcl(cnt, t, lw, &tot);       // local digit start
    unsigned tot2;
    unsigned dbase = blockScanExcl(dtot[d], t, lw, &tot2);  // global digit base
    if (MODE == 4){
      unsigned incl = dbase + dtot[d];                      // == k_cut arithmetic
      if (dbase < R_N && incl >= R_N) cutm = incl;
    }
    gput[d] = dbase + gh[d * NTILES + blockIdx.x] - ldig;
    wrun[d]       = ldig;
    wrun[256 + d] = ldig + c0;
    wrun[512 + d] = ldig + c0 + c1;
    wrun[768 + d] = ldig + c0 + c1 + c2;
  }
  __syncthreads();
  if (MODE == 4){
    M = cutm;
    if (blockIdx.x == 0u && t == 0u) mout[0] = M;           // for later kernels
  }
  #pragma unroll
  for (int r = 0; r < WPT; r++)
    stage[ wrun[w*256 + dg[r]] + rnk[r] ] = elems[r];
  __syncthreads();
  #pragma unroll
  for (int r = 0; r < WPT; r++){
    unsigned j = (unsigned)r * 256u + t;
    uint64_t e = stage[j];
    unsigned d = (unsigned)((e >> shift) & 0xFF);
    unsigned dest = gput[d] + j;
    if (MODE == 2){
      if (dest < R_N){
        uint32_t key = (uint32_t)(e >> 32);
        fout[2u*dest]        = (float)(key >> 12);
        fout[2u*dest + 1u]   = (float)(key & 4095u);
        fout[2u*R_N + dest]  = __uint_as_float(~(uint32_t)e);
      }
    } else if (MODE == 1 || MODE == 4){
      if (dest < M) out[dest] = e;
    } else {
      out[dest] = e;
    }
  }
}

__global__ __launch_bounds__(256) void k_scatter(const uint64_t* __restrict__ in,
                                                 uint64_t* __restrict__ out,
                                                 unsigned shift,
                                                 const unsigned* __restrict__ gh,
                                                 const unsigned* __restrict__ dtot){
  scatter_body<0>(in, out, nullptr, shift, gh, dtot, nullptr, nullptr,
                  nullptr, nullptr, nullptr, nullptr, nullptr, nullptr);
}

__global__ __launch_bounds__(256) void k_scatter_b(const int* __restrict__ sidx,
                                                   const int* __restrict__ ridx,
                                                   const float* __restrict__ rval,
                                                   const float* __restrict__ grad,
                                                   uint64_t* __restrict__ out,
                                                   unsigned shift,
                                                   const unsigned* __restrict__ gh,
                                                   const unsigned* __restrict__ dtot){
  scatter_body<3>(nullptr, out, nullptr, shift, gh, dtot, nullptr, nullptr,
                  sidx, ridx, rval, grad, nullptr, nullptr);
}

__global__ __launch_bounds__(256) void k_scatter_m(const uint64_t* __restrict__ in,
                                                   uint64_t* __restrict__ out,
                                                   unsigned shift,
                                                   const unsigned* __restrict__ gh,
                                                   const unsigned* __restrict__ dtot,
                                                   const unsigned* __restrict__ nsyn,
                                                   const unsigned* __restrict__ mskip){
  scatter_body<1>(in, out, nullptr, shift, gh, dtot, nsyn, mskip,
                  nullptr, nullptr, nullptr, nullptr, nullptr, nullptr);
}

__global__ __launch_bounds__(256) void k_scatter_mg(const uint64_t* __restrict__ in,
                                                    uint64_t* __restrict__ out,
                                                    unsigned shift,
                                                    const unsigned* __restrict__ gh,
                                                    const unsigned* __restrict__ dtot,
                                                    const unsigned* __restrict__ hcnt,
                                                    unsigned* __restrict__ mout){
  scatter_body<4>(in, out, nullptr, shift, gh, dtot, nullptr, nullptr,
                  nullptr, nullptr, nullptr, nullptr, hcnt, mout);
}

__global__ __launch_bounds__(256) void k_scatter_out(const uint64_t* __restrict__ in,
                                                     float* __restrict__ fout,
                                                     unsigned shift,
                                                     const unsigned* __restrict__ gh,
                                                     const unsigned* __restrict__ dtot,
                                                     const unsigned* __restrict__ nsyn){
  scatter_body<2>(in, nullptr, fout, shift, gh, dtot, nsyn, nsyn,
                  nullptr, nullptr, nullptr, nullptr, nullptr, nullptr);
}

// In-order segmented sum, GAPPED OUTPUT: one thread per element (proven shape;
// TLP hides the serial walks). Each block writes its candidates densely into
// its OWN 256-slot region out[b*256 + rank] and records hcnt[b] = count.
// No cross-block prefix needed -> headcount/scanheads kernels deleted.
// Candidate order (block asc, rank asc) remains globally key-ascending.
__global__ __launch_bounds__(256) void k_segsum2(const uint64_t* __restrict__ in,
                                                 uint64_t* __restrict__ out,
                                                 unsigned* __restrict__ hcnt){
  __shared__ unsigned wc[4], woffs[4];
  unsigned t = threadIdx.x, lane = t & 63u, w = t >> 6;
  size_t p = (size_t)blockIdx.x * 256 + t;
  uint64_t e0 = in[p];
  uint32_t k = (uint32_t)(e0 >> 32);
  bool head = ((p == 0) || ((uint32_t)(in[p-1] >> 32) != k)) && ((uint32_t)e0 != PAD_VAL);
  uint64_t m = __ballot(head);
  if (lane == 0) wc[w] = (unsigned)__popcll(m);
  __syncthreads();
  if (t == 0){
    unsigned a = 0;
    for (int i = 0; i < 4; i++){ woffs[i] = a; a += wc[i]; }
    hcnt[blockIdx.x] = a;
  }
  __syncthreads();
  if (head){
    uint64_t ltm = (lane == 0) ? 0ull : (~0ull >> (64u - lane));
    unsigned rank = (unsigned)__popcll(m & ltm);
    unsigned oidx = blockIdx.x * 256u + woffs[w] + rank;
    float s = __uint_as_float((uint32_t)e0);
    size_t q = p + 1;
    while (q < NPAD){
      uint64_t e = in[q];
      if ((uint32_t)(e >> 32) != k) break;
      uint32_t vb = (uint32_t)e;
      if (vb == PAD_VAL) break;
      s += __uint_as_float(vb);
      q++;
    }
    out[oidx] = ((uint64_t)k << 32) | (uint64_t)(uint32_t)(~__float_as_uint(s));
  }
}

extern "C" void kernel_launch(void* const* d_in, const int* in_sizes, int n_in,
                              void* d_out, int out_size, void* d_ws, size_t ws_size,
                              hipStream_t stream) {
  const int*   sidx = (const int*)d_in[0];
  const int*   ridx = (const int*)d_in[1];
  const float* rval = (const float*)d_in[2];
  const float* grad = (const float*)d_in[3];
  float* out = (float*)d_out;

  uint64_t* A0   = (uint64_t*)d_ws;                       // 35.3 MB
  uint64_t* A1   = A0 + NPAD;                             // 35.3 MB
  unsigned* gh   = (unsigned*)(A1 + NPAD);                // 1.1 MB
  unsigned* dtot = gh + 256 * NTILES;                     // 1 KB
  unsigned* hcnt = dtot + 256;                            // 67 KB
  unsigned* mvar = hcnt + NSB;                            // 4 B

  // Stable key sort: 24 bits, 3 x 8-bit passes. Pass 1 recomputes elements
  // from the raw inputs (no element-array build/read). inputs->A1->A0->A1.
  k_hist0    <<<NTILES, 256, 0, stream>>>(sidx, ridx, gh);
  k_scanrows <<<256,    256, 0, stream>>>(gh, dtot);
  k_scatter_b<<<NTILES, 256, 0, stream>>>(sidx, ridx, rval, grad, A1, 32, gh, dtot);
  k_hist     <<<NTILES, 256, 0, stream>>>(A1, 40, gh);
  k_scanrows <<<256,    256, 0, stream>>>(gh, dtot);
  k_scatter  <<<NTILES, 256, 0, stream>>>(A1, A0, 40, gh, dtot);
  k_hist     <<<NTILES, 256, 0, stream>>>(A0, 48, gh);
  k_scanrows <<<256,    256, 0, stream>>>(gh, dtot);
  k_scatter  <<<NTILES, 256, 0, stream>>>(A0, A1, 48, gh, dtot);

  // Coalesce, gapped: per-256-block dense candidates + hcnt. 1 dispatch,
  // no headcount read, no scanheads.
  k_segsum2<<<NSB, 256, 0, stream>>>(A1, A0, hcnt);

  // Select over the gapped layout: byte-24 histogram with per-block validity,
  // then gapped compact scatter with fused cut (M persisted to mvar).
  // Output A1[0, M) is dense.
  k_hist_syn2<<<NTILES, 256, 0, stream>>>(A0, 24, gh, hcnt);
  k_scanrows <<<256,    256, 0, stream>>>(gh, dtot);
  k_scatter_mg<<<NTILES, 256, 0, stream>>>(A0, A1, 24, gh, dtot, hcnt, mvar);

  // Stable value sort over only M elements: 4 x 8-bit LSD passes,
  // final pass fused with output emission. A1->A0->A1->A0->out.
  k_hist_syn <<<NTILES, 256, 0, stream>>>(A1, 0, gh, mvar);
  k_scanrows <<<256,    256, 0, stream>>>(gh, dtot);
  k_scatter_m<<<NTILES, 256, 0, stream>>>(A1, A0, 0, gh, dtot, mvar, mvar);
  k_hist_syn <<<NTILES, 256, 0, stream>>>(A0, 8, gh, mvar);
  k_scanrows <<<256,    256, 0, stream>>>(gh, dtot);
  k_scatter_m<<<NTILES, 256, 0, stream>>>(A0, A1, 8, gh, dtot, mvar, mvar);
  k_hist_syn <<<NTILES, 256, 0, stream>>>(A1, 16, gh, mvar);
  k_scanrows <<<256,    256, 0, stream>>>(gh, dtot);
  k_scatter_m<<<NTILES, 256, 0, stream>>>(A1, A0, 16, gh, dtot, mvar, mvar);
  k_hist_syn   <<<NTILES, 256, 0, stream>>>(A0, 24, gh, mvar);
  k_scanrows   <<<256,    256, 0, stream>>>(gh, dtot);
  k_scatter_out<<<NTILES, 256, 0, stream>>>(A0, out, 24, gh, dtot, mvar);
}